// Round 11
// baseline (344.592 us; speedup 1.0000x reference)
//
#include <hip/hip_runtime.h>
#include <hip/hip_bf16.h>
#include <math.h>

#define N_NODES 50000
#define N_EDGES 640000
#define IN_DIM 5
#define HID 128
#define NGRAPH 512
#define SCAN_NBLK ((N_NODES + 255) / 256)  // 196
#define GEMM_NBLK ((N_NODES + 63) / 64)    // 782
#define PCHUNK 8
#define PNW ((N_NODES + PCHUNK - 1) / PCHUNK)  // 6250
#define CNT_BLK ((N_EDGES + 255) / 256)        // 2500
#define PREP_BLK 256
#define PROJ_BLK ((N_NODES * HID + 255) / 256) // 25000

typedef unsigned short u16;
typedef __attribute__((ext_vector_type(8))) short bf16x8;
typedef __attribute__((ext_vector_type(8))) unsigned short u16x8;
typedef __attribute__((ext_vector_type(4))) float f32x4;
typedef __attribute__((ext_vector_type(8))) float f32x8;

__device__ __forceinline__ float bf2f(u16 u) {
  union { unsigned int i; float f; } v; v.i = ((unsigned int)u) << 16; return v.f;
}
__device__ __forceinline__ u16 f2bf(float f) {
  return __bfloat16_as_ushort(__float2bfloat16(f));
}

// ---------------- Fused setup: count_edges + weight prep + layer0 rel proj ----------------
__global__ __launch_bounds__(256) void setup_k(const int* __restrict__ dst,
                                               int* __restrict__ counts,
                                               const float* __restrict__ W1rel,
                                               const float* __restrict__ W1root,
                                               const float* __restrict__ W2rel,
                                               const float* __restrict__ W2root,
                                               u16* __restrict__ T1rel, u16* __restrict__ T1root,
                                               u16* __restrict__ T2rel, u16* __restrict__ T2root,
                                               const float* __restrict__ x,
                                               const float* __restrict__ Wrel0,
                                               u16* __restrict__ Z) {
  int b = blockIdx.x;
  if (b < CNT_BLK) {
    int e = b * 256 + threadIdx.x;
    if (e < N_EDGES) atomicAdd(&counts[dst[e]], 1);
  } else if (b < CNT_BLK + PREP_BLK) {
    int bb = b - CNT_BLK;
    int which = bb >> 6;
    int idx = (bb & 63) * 256 + threadIdx.x;  // k*128 + n
    const float* W = which == 0 ? W1rel : which == 1 ? W1root : which == 2 ? W2rel : W2root;
    u16* T = which == 0 ? T1rel : which == 1 ? T1root : which == 2 ? T2rel : T2root;
    int k = idx >> 7, n = idx & 127;
    T[n * HID + k] = f2bf(W[idx]);
  } else {
    int idx = (b - CNT_BLK - PREP_BLK) * 256 + threadIdx.x;  // node*128 + c
    if (idx < N_NODES * HID) {
      int i = idx >> 7, c = idx & 127;
      float zr = 0.f;
#pragma unroll
      for (int k = 0; k < IN_DIM; ++k) zr = fmaf(x[i * IN_DIM + k], Wrel0[k * HID + c], zr);
      Z[idx] = f2bf(zr);
    }
  }
}

__global__ __launch_bounds__(256) void partial_k(const int* __restrict__ counts,
                                                 int* __restrict__ bsum) {
  int t = threadIdx.x;
  int i = blockIdx.x * 256 + t;
  int v = (i < N_NODES) ? counts[i] : 0;
#pragma unroll
  for (int off = 32; off; off >>= 1) v += __shfl_down(v, off, 64);
  __shared__ int ws[4];
  if ((t & 63) == 0) ws[t >> 6] = v;
  __syncthreads();
  if (t == 0) bsum[blockIdx.x] = ws[0] + ws[1] + ws[2] + ws[3];
}

__global__ __launch_bounds__(256) void scanb_k(const int* __restrict__ bsum,
                                               int* __restrict__ boff,
                                               int* __restrict__ row_ptr) {
  __shared__ int s[256];
  int t = threadIdx.x;
  int v = (t < SCAN_NBLK) ? bsum[t] : 0;
  s[t] = v;
  __syncthreads();
#pragma unroll
  for (int off = 1; off < 256; off <<= 1) {
    int u = (t >= off) ? s[t - off] : 0;
    __syncthreads();
    s[t] += u;
    __syncthreads();
  }
  if (t < SCAN_NBLK) boff[t] = s[t] - v;
  if (t == 255) row_ptr[N_NODES] = s[255];
}

__global__ __launch_bounds__(256) void write_scan_k(const int* __restrict__ counts,
                                                    const int* __restrict__ boff,
                                                    int* __restrict__ row_ptr,
                                                    int* __restrict__ fill_off) {
  __shared__ int s[256];
  int t = threadIdx.x;
  int i = blockIdx.x * 256 + t;
  int c = (i < N_NODES) ? counts[i] : 0;
  s[t] = c;
  __syncthreads();
#pragma unroll
  for (int off = 1; off < 256; off <<= 1) {
    int u = (t >= off) ? s[t - off] : 0;
    __syncthreads();
    s[t] += u;
    __syncthreads();
  }
  int excl = s[t] - c + boff[blockIdx.x];
  if (i < N_NODES) {
    row_ptr[i] = excl;
    fill_off[i] = excl;
  }
}

__global__ void fill_edges_k(const int* __restrict__ src, const int* __restrict__ dst,
                             int* __restrict__ fill_off, int* __restrict__ esrc) {
  int e = blockIdx.x * blockDim.x + threadIdx.x;
  if (e < N_EDGES) {
    int d = dst[e];
    int pos = atomicAdd(&fill_off[d], 1);
    esrc[pos] = src[e];
  }
}

// ---------------- MFMA GEMM for layers 1,2 ----------------
__global__ __launch_bounds__(256, 3) void gemm_mfma_k(const u16* __restrict__ A,
                                                      const u16* __restrict__ WrelT,
                                                      const u16* __restrict__ WrootT,
                                                      const float* __restrict__ bias,
                                                      u16* __restrict__ Z,
                                                      void* __restrict__ R,
                                                      int r_is_f32) {
  __shared__ u16 As[64][136];  // pad +8 bf16 -> 2-way max bank aliasing (free)
  int tid = threadIdx.x;
  int wv = tid >> 6, lane = tid & 63;
  int m = lane & 15, quad = lane >> 4;
  int r0 = blockIdx.x * 64;

#pragma unroll
  for (int it = 0; it < 4; ++it) {
    int idx = it * 256 + tid;
    int row = idx >> 4, q = idx & 15;
    int grow = r0 + row;
    float4 v = make_float4(0.f, 0.f, 0.f, 0.f);
    if (grow < N_NODES) v = *(const float4*)(A + (size_t)grow * HID + q * 8);
    *(float4*)&As[row][q * 8] = v;
  }
  __syncthreads();

  const u16* WT = (wv < 2) ? WrelT : WrootT;
  int n0 = (wv & 1) * 64;

  f32x4 acc[4][4];
#pragma unroll
  for (int mt = 0; mt < 4; ++mt)
#pragma unroll
    for (int nt = 0; nt < 4; ++nt) acc[mt][nt] = (f32x4){0.f, 0.f, 0.f, 0.f};

#pragma unroll
  for (int ks = 0; ks < 4; ++ks) {
    int kb = ks * 32;
    bf16x8 af[4], bf[4];
#pragma unroll
    for (int mt = 0; mt < 4; ++mt)
      af[mt] = *(const bf16x8*)&As[mt * 16 + m][kb + quad * 8];
#pragma unroll
    for (int nt = 0; nt < 4; ++nt)
      bf[nt] = *(const bf16x8*)(WT + (size_t)(n0 + nt * 16 + m) * HID + kb + quad * 8);
#pragma unroll
    for (int mt = 0; mt < 4; ++mt)
#pragma unroll
      for (int nt = 0; nt < 4; ++nt)
        acc[mt][nt] = __builtin_amdgcn_mfma_f32_16x16x32_bf16(af[mt], bf[nt], acc[mt][nt], 0, 0, 0);
  }

  // Epilogue. C/D layout: col = lane&15, row = quad*4 + reg.
  if (wv < 2) {
#pragma unroll
    for (int mt = 0; mt < 4; ++mt) {
#pragma unroll
      for (int nt = 0; nt < 4; ++nt) {
        int col = n0 + nt * 16 + m;
#pragma unroll
        for (int r = 0; r < 4; ++r) {
          int row = r0 + mt * 16 + quad * 4 + r;
          if (row < N_NODES) Z[(size_t)row * HID + col] = f2bf(acc[mt][nt][r]);
        }
      }
    }
  } else {
    float bl[4];
#pragma unroll
    for (int nt = 0; nt < 4; ++nt) bl[nt] = bias[n0 + nt * 16 + m];
#pragma unroll
    for (int mt = 0; mt < 4; ++mt) {
#pragma unroll
      for (int nt = 0; nt < 4; ++nt) {
        int col = n0 + nt * 16 + m;
#pragma unroll
        for (int r = 0; r < 4; ++r) {
          int row = r0 + mt * 16 + quad * 4 + r;
          if (row < N_NODES) {
            float v = acc[mt][nt][r] + bl[nt];
            if (r_is_f32) ((float*)R)[(size_t)row * HID + col] = v;
            else          ((u16*)R)[(size_t)row * HID + col] = f2bf(v);
          }
        }
      }
    }
  }
}

// ---- gather helper: predicated unroll x4 -> 4 edges in flight per quarter ----
// (round-10 lesson: avg deg/quarter = 3.2, so a >=4-edge main loop never runs;
// predication makes the FIRST round issue all 4 loads for typical nodes.)
__device__ __forceinline__ void gather_node(const u16* __restrict__ Z,
                                            const int* __restrict__ esrc,
                                            int beg, int end, int q, int f8,
                                            f32x8& out) {
  f32x8 a0, a1, a2, a3;
#pragma unroll
  for (int j = 0; j < 8; ++j) { a0[j] = 0.f; a1[j] = 0.f; a2[j] = 0.f; a3[j] = 0.f; }
  for (int e = beg + q; e < end; e += 16) {
    bool p1 = e + 4 < end, p2 = e + 8 < end, p3 = e + 12 < end;
    int s0 = esrc[e];
    int s1 = p1 ? esrc[e + 4] : s0;
    int s2 = p2 ? esrc[e + 8] : s0;
    int s3 = p3 ? esrc[e + 12] : s0;
    u16x8 z0 = *(const u16x8*)(Z + (size_t)s0 * HID + f8);
    u16x8 z1 = *(const u16x8*)(Z + (size_t)s1 * HID + f8);
    u16x8 z2 = *(const u16x8*)(Z + (size_t)s2 * HID + f8);
    u16x8 z3 = *(const u16x8*)(Z + (size_t)s3 * HID + f8);
#pragma unroll
    for (int j = 0; j < 8; ++j) {
      a0[j] += bf2f(z0[j]);
      a1[j] += p1 ? bf2f(z1[j]) : 0.f;
      a2[j] += p2 ? bf2f(z2[j]) : 0.f;
      a3[j] += p3 ? bf2f(z3[j]) : 0.f;
    }
  }
#pragma unroll
  for (int j = 0; j < 8; ++j) out[j] = (a0[j] + a1[j]) + (a2[j] + a3[j]);
}

// ---------------- Edge aggregation (layers 0,1), OUT bf16 + ReLU ----------------
// mode 0: OUT bf16 rmw + ReLU.  mode 2: OUT = relu(x@Wroot0 + b0 + gather).
__global__ __launch_bounds__(256) void agg_k(const u16* __restrict__ Z,
                                             const int* __restrict__ row_ptr,
                                             const int* __restrict__ esrc,
                                             u16* __restrict__ OUT, int mode,
                                             const float* __restrict__ x,
                                             const float* __restrict__ Wroot,
                                             const float* __restrict__ bias) {
  int wave = threadIdx.x >> 6;
  int lane = threadIdx.x & 63;
  int node = blockIdx.x * 4 + wave;
  if (node >= N_NODES) return;
  int q = lane >> 4;        // 0..3
  int f8 = (lane & 15) * 8; // 8 features/lane
  int beg = row_ptr[node], end = row_ptr[node + 1];
  f32x8 acc;
  gather_node(Z, esrc, beg, end, q, f8, acc);
#pragma unroll
  for (int j = 0; j < 8; ++j) {
    acc[j] += __shfl_xor(acc[j], 16, 64);
    acc[j] += __shfl_xor(acc[j], 32, 64);
  }
  if (q == 0) {
    u16* o = OUT + (size_t)node * HID + f8;
    u16x8 w8;
    if (mode == 0) {
      u16x8 o8 = *(const u16x8*)o;
#pragma unroll
      for (int j = 0; j < 8; ++j) w8[j] = f2bf(fmaxf(bf2f(o8[j]) + acc[j], 0.f));
    } else {
      float xr[IN_DIM];
#pragma unroll
      for (int k = 0; k < IN_DIM; ++k) xr[k] = x[node * IN_DIM + k];
#pragma unroll
      for (int j = 0; j < 8; ++j) {
        float r = bias[f8 + j];
#pragma unroll
        for (int k = 0; k < IN_DIM; ++k) r = fmaf(xr[k], Wroot[k * HID + f8 + j], r);
        w8[j] = f2bf(fmaxf(r + acc[j], 0.f));
      }
    }
    *(u16x8*)o = w8;
  }
}

// ---------------- Fused layer-2 agg + mean pool ----------------
// Quarter-private accumulators; shfl reduction only at segment-boundary flush.
__global__ __launch_bounds__(256) void pool_fused_k(const u16* __restrict__ Z,
                                                    const float* __restrict__ ROOT,
                                                    const int* __restrict__ row_ptr,
                                                    const int* __restrict__ esrc,
                                                    const int* __restrict__ batch,
                                                    float* __restrict__ pool,
                                                    int* __restrict__ cnt) {
  int wave = blockIdx.x * 4 + (threadIdx.x >> 6);
  int lane = threadIdx.x & 63;
  if (wave >= PNW) return;
  int q = lane >> 4;
  int f8 = (lane & 15) * 8;
  int n0 = wave * PCHUNK;
  int n1 = n0 + PCHUNK;
  if (n1 > N_NODES) n1 = N_NODES;
  int cur = batch[n0];
  int run = 0;
  float pacc[8];
#pragma unroll
  for (int j = 0; j < 8; ++j) pacc[j] = 0.f;

  auto flush = [&](int g) {
#pragma unroll
    for (int j = 0; j < 8; ++j) {
      pacc[j] += __shfl_xor(pacc[j], 16, 64);
      pacc[j] += __shfl_xor(pacc[j], 32, 64);
    }
    if (q == 0) {
#pragma unroll
      for (int j = 0; j < 8; ++j) atomicAdd(&pool[(size_t)g * HID + f8 + j], pacc[j]);
    }
    if (lane == 0) atomicAdd(&cnt[g], run);
#pragma unroll
    for (int j = 0; j < 8; ++j) pacc[j] = 0.f;
    run = 0;
  };

  for (int n = n0; n < n1; ++n) {
    int g = batch[n];  // wave-uniform
    if (g != cur) { flush(cur); cur = g; }
    int beg = row_ptr[n], end = row_ptr[n + 1];
    f32x8 acc;
    gather_node(Z, esrc, beg, end, q, f8, acc);
#pragma unroll
    for (int j = 0; j < 8; ++j) pacc[j] += acc[j];
    if ((n & 3) == q) {
      const float* rp = ROOT + (size_t)n * HID + f8;
      float4 ra = *(const float4*)rp;
      float4 rb = *(const float4*)(rp + 4);
      pacc[0] += ra.x; pacc[1] += ra.y; pacc[2] += ra.z; pacc[3] += ra.w;
      pacc[4] += rb.x; pacc[5] += rb.y; pacc[6] += rb.z; pacc[7] += rb.w;
    }
    run += 1;
  }
  flush(cur);
}

// ---------------- Final: sigmoid(pool/cnt @ Wlin + b) ----------------
__global__ __launch_bounds__(256) void final_k(const float* __restrict__ pool,
                                               const int* __restrict__ cnt,
                                               const float* __restrict__ Wlin,
                                               const float* __restrict__ blin,
                                               float* __restrict__ out) {
  int wave = threadIdx.x >> 6;
  int lane = threadIdx.x & 63;
  int g = blockIdx.x * 4 + wave;
  if (g >= NGRAPH) return;
  float2 p = *(const float2*)&pool[(size_t)g * HID + lane * 2];
  float v = p.x * Wlin[lane * 2 + 0] + p.y * Wlin[lane * 2 + 1];
#pragma unroll
  for (int off = 32; off; off >>= 1) v += __shfl_down(v, off, 64);
  if (lane == 0) {
    float c = (float)cnt[g];
    if (c < 1.f) c = 1.f;
    float logit = v / c + blin[0];
    out[g] = 1.f / (1.f + expf(-logit));
  }
}

extern "C" void kernel_launch(void* const* d_in, const int* in_sizes, int n_in,
                              void* d_out, int out_size, void* d_ws, size_t ws_size,
                              hipStream_t stream) {
  const float* x      = (const float*)d_in[0];
  const int*   ei     = (const int*)d_in[1];
  const int*   batch  = (const int*)d_in[2];
  const float* Wrel0  = (const float*)d_in[3];
  const float* brel0  = (const float*)d_in[4];
  const float* Wroot0 = (const float*)d_in[5];
  const float* Wrel1  = (const float*)d_in[6];
  const float* brel1  = (const float*)d_in[7];
  const float* Wroot1 = (const float*)d_in[8];
  const float* Wrel2  = (const float*)d_in[9];
  const float* brel2  = (const float*)d_in[10];
  const float* Wroot2 = (const float*)d_in[11];
  const float* Wlin   = (const float*)d_in[12];
  const float* blin   = (const float*)d_in[13];
  float* out = (float*)d_out;
  const int* srcp = ei;
  const int* dstp = ei + N_EDGES;

  char* ws = (char*)d_ws;
  size_t off = 0;
  auto alloc = [&](size_t b) { size_t o = off; off += (b + 255) & ~(size_t)255; return o; };
  u16*  Z     = (u16*)(ws + alloc(sizeof(u16) * N_NODES * HID));
  u16*  HA    = (u16*)(ws + alloc(sizeof(u16) * N_NODES * HID));
  u16*  HB    = (u16*)(ws + alloc(sizeof(u16) * N_NODES * HID));
  float* OUTF = (float*)(ws + alloc(sizeof(float) * N_NODES * HID));
  u16* WT1rel = (u16*)(ws + alloc(sizeof(u16) * HID * HID));
  u16* WT1root= (u16*)(ws + alloc(sizeof(u16) * HID * HID));
  u16* WT2rel = (u16*)(ws + alloc(sizeof(u16) * HID * HID));
  u16* WT2root= (u16*)(ws + alloc(sizeof(u16) * HID * HID));
  int* row_ptr  = (int*)(ws + alloc(sizeof(int) * (N_NODES + 1)));
  int* esrc     = (int*)(ws + alloc(sizeof(int) * N_EDGES));
  int* fill_off = (int*)(ws + alloc(sizeof(int) * N_NODES));
  int* bsum     = (int*)(ws + alloc(sizeof(int) * 256));
  int* boff     = (int*)(ws + alloc(sizeof(int) * 256));
  size_t zero_base = off;
  int* counts  = (int*)(ws + alloc(sizeof(int) * N_NODES));
  float* pool  = (float*)(ws + alloc(sizeof(float) * NGRAPH * HID));
  int* cnt     = (int*)(ws + alloc(sizeof(int) * NGRAPH));
  size_t zero_len = off - zero_base;

  hipMemsetAsync(ws + zero_base, 0, zero_len, stream);

  setup_k<<<CNT_BLK + PREP_BLK + PROJ_BLK, 256, 0, stream>>>(
      dstp, counts, Wrel1, Wroot1, Wrel2, Wroot2,
      WT1rel, WT1root, WT2rel, WT2root, x, Wrel0, Z);
  partial_k<<<SCAN_NBLK, 256, 0, stream>>>(counts, bsum);
  scanb_k<<<1, 256, 0, stream>>>(bsum, boff, row_ptr);
  write_scan_k<<<SCAN_NBLK, 256, 0, stream>>>(counts, boff, row_ptr, fill_off);
  fill_edges_k<<<(N_EDGES + 255) / 256, 256, 0, stream>>>(srcp, dstp, fill_off, esrc);

  // Layer 0: agg mode 2 computes root-init inline
  agg_k<<<(N_NODES + 3) / 4, 256, 0, stream>>>(Z, row_ptr, esrc, HA, 2, x, Wroot0, brel0);
  // Layer 1
  gemm_mfma_k<<<GEMM_NBLK, 256, 0, stream>>>(HA, WT1rel, WT1root, brel1, Z, HB, 0);
  agg_k<<<(N_NODES + 3) / 4, 256, 0, stream>>>(Z, row_ptr, esrc, HB, 0, nullptr, nullptr, nullptr);
  // Layer 2: gemm -> Z (rel, bf16) + OUTF (root+bias, f32); fused agg+pool
  gemm_mfma_k<<<GEMM_NBLK, 256, 0, stream>>>(HB, WT2rel, WT2root, brel2, Z, OUTF, 1);
  pool_fused_k<<<(PNW + 3) / 4, 256, 0, stream>>>(Z, OUTF, row_ptr, esrc, batch, pool, cnt);

  final_k<<<(NGRAPH + 3) / 4, 256, 0, stream>>>(pool, cnt, Wlin, blin, out);
}

// Round 12
// 303.716 us; speedup vs baseline: 1.1346x; 1.1346x over previous
//
#include <hip/hip_runtime.h>
#include <hip/hip_bf16.h>
#include <math.h>

#define N_NODES 50000
#define N_EDGES 640000
#define IN_DIM 5
#define HID 128
#define NGRAPH 512
#define SCAN_NBLK ((N_NODES + 255) / 256)  // 196
#define GEMM_NBLK ((N_NODES + 63) / 64)    // 782
#define PCHUNK 8
#define PNW ((N_NODES + PCHUNK - 1) / PCHUNK)  // 6250
#define CNT_BLK ((N_EDGES + 255) / 256)        // 2500
#define PREP_BLK 256

typedef unsigned short u16;
typedef __attribute__((ext_vector_type(8))) short bf16x8;
typedef __attribute__((ext_vector_type(8))) unsigned short u16x8;
typedef __attribute__((ext_vector_type(4))) float f32x4;
typedef __attribute__((ext_vector_type(8))) float f32x8;

__device__ __forceinline__ float bf2f(u16 u) {
  union { unsigned int i; float f; } v; v.i = ((unsigned int)u) << 16; return v.f;
}
__device__ __forceinline__ u16 f2bf(float f) {
  return __bfloat16_as_ushort(__float2bfloat16(f));
}

// ---------------- Fused setup: count_edges + weight prep ----------------
__global__ __launch_bounds__(256) void setup_k(const int* __restrict__ dst,
                                               int* __restrict__ counts,
                                               const float* __restrict__ W1rel,
                                               const float* __restrict__ W1root,
                                               const float* __restrict__ W2rel,
                                               const float* __restrict__ W2root,
                                               u16* __restrict__ T1rel, u16* __restrict__ T1root,
                                               u16* __restrict__ T2rel, u16* __restrict__ T2root) {
  int b = blockIdx.x;
  if (b < CNT_BLK) {
    int e = b * 256 + threadIdx.x;
    if (e < N_EDGES) atomicAdd(&counts[dst[e]], 1);
  } else {
    int bb = b - CNT_BLK;
    int which = bb >> 6;
    int idx = (bb & 63) * 256 + threadIdx.x;  // k*128 + n
    const float* W = which == 0 ? W1rel : which == 1 ? W1root : which == 2 ? W2rel : W2root;
    u16* T = which == 0 ? T1rel : which == 1 ? T1root : which == 2 ? T2rel : T2root;
    int k = idx >> 7, n = idx & 127;
    T[n * HID + k] = f2bf(W[idx]);
  }
}

__global__ __launch_bounds__(256) void partial_k(const int* __restrict__ counts,
                                                 int* __restrict__ bsum) {
  int t = threadIdx.x;
  int i = blockIdx.x * 256 + t;
  int v = (i < N_NODES) ? counts[i] : 0;
#pragma unroll
  for (int off = 32; off; off >>= 1) v += __shfl_down(v, off, 64);
  __shared__ int ws[4];
  if ((t & 63) == 0) ws[t >> 6] = v;
  __syncthreads();
  if (t == 0) bsum[blockIdx.x] = ws[0] + ws[1] + ws[2] + ws[3];
}

__global__ __launch_bounds__(256) void scanb_k(const int* __restrict__ bsum,
                                               int* __restrict__ boff,
                                               int* __restrict__ row_ptr) {
  __shared__ int s[256];
  int t = threadIdx.x;
  int v = (t < SCAN_NBLK) ? bsum[t] : 0;
  s[t] = v;
  __syncthreads();
#pragma unroll
  for (int off = 1; off < 256; off <<= 1) {
    int u = (t >= off) ? s[t - off] : 0;
    __syncthreads();
    s[t] += u;
    __syncthreads();
  }
  if (t < SCAN_NBLK) boff[t] = s[t] - v;
  if (t == 255) row_ptr[N_NODES] = s[255];
}

__global__ __launch_bounds__(256) void write_scan_k(const int* __restrict__ counts,
                                                    const int* __restrict__ boff,
                                                    int* __restrict__ row_ptr,
                                                    int* __restrict__ fill_off) {
  __shared__ int s[256];
  int t = threadIdx.x;
  int i = blockIdx.x * 256 + t;
  int c = (i < N_NODES) ? counts[i] : 0;
  s[t] = c;
  __syncthreads();
#pragma unroll
  for (int off = 1; off < 256; off <<= 1) {
    int u = (t >= off) ? s[t - off] : 0;
    __syncthreads();
    s[t] += u;
    __syncthreads();
  }
  int excl = s[t] - c + boff[blockIdx.x];
  if (i < N_NODES) {
    row_ptr[i] = excl;
    fill_off[i] = excl;
  }
}

__global__ void fill_edges_k(const int* __restrict__ src, const int* __restrict__ dst,
                             int* __restrict__ fill_off, int* __restrict__ esrc) {
  int e = blockIdx.x * blockDim.x + threadIdx.x;
  if (e < N_EDGES) {
    int d = dst[e];
    int pos = atomicAdd(&fill_off[d], 1);
    esrc[pos] = src[e];
  }
}

// ---------------- Layer-0 gather in INPUT space (5-dim): 20B/edge, not 256B ----
// segsum(x@W) == segsum(x)@W. Quarter (16 lanes) per node, lane per edge ->
// 16 edges in flight; shfl-reduce width 16.
__global__ __launch_bounds__(256) void gather_x_k(const float* __restrict__ x,
                                                  const int* __restrict__ row_ptr,
                                                  const int* __restrict__ esrc,
                                                  float* __restrict__ aggx) {
  int wave = blockIdx.x * 4 + (threadIdx.x >> 6);
  int lane = threadIdx.x & 63;
  int node = wave * 4 + (lane >> 4);
  if (node >= N_NODES) return;
  int l16 = lane & 15;
  int beg = row_ptr[node], end = row_ptr[node + 1];
  float a[IN_DIM];
#pragma unroll
  for (int k = 0; k < IN_DIM; ++k) a[k] = 0.f;
  for (int e = beg + l16; e < end; e += 16) {
    int s = esrc[e];
#pragma unroll
    for (int k = 0; k < IN_DIM; ++k) a[k] += x[s * IN_DIM + k];
  }
#pragma unroll
  for (int k = 0; k < IN_DIM; ++k) {
    a[k] += __shfl_xor(a[k], 1, 16);
    a[k] += __shfl_xor(a[k], 2, 16);
    a[k] += __shfl_xor(a[k], 4, 16);
    a[k] += __shfl_xor(a[k], 8, 16);
  }
  if (l16 == 0) {
#pragma unroll
    for (int k = 0; k < IN_DIM; ++k) aggx[node * IN_DIM + k] = a[k];
  }
}

// ---------------- Layer 0: HA = relu(aggx@Wrel0 + x@Wroot0 + brel0), bf16 ----------------
__global__ void proj_l0_k(const float* __restrict__ aggx, const float* __restrict__ x,
                          const float* __restrict__ Wrel, const float* __restrict__ Wroot,
                          const float* __restrict__ bias, u16* __restrict__ HA) {
  int idx = blockIdx.x * blockDim.x + threadIdx.x;  // node*128 + c
  if (idx >= N_NODES * HID) return;
  int i = idx >> 7, c = idx & 127;
  float v = bias[c];
#pragma unroll
  for (int k = 0; k < IN_DIM; ++k) {
    v = fmaf(aggx[i * IN_DIM + k], Wrel[k * HID + c], v);
    v = fmaf(x[i * IN_DIM + k], Wroot[k * HID + c], v);
  }
  HA[idx] = f2bf(fmaxf(v, 0.f));
}

// ---------------- MFMA GEMM for layers 1,2 ----------------
__global__ __launch_bounds__(256, 3) void gemm_mfma_k(const u16* __restrict__ A,
                                                      const u16* __restrict__ WrelT,
                                                      const u16* __restrict__ WrootT,
                                                      const float* __restrict__ bias,
                                                      u16* __restrict__ Z,
                                                      void* __restrict__ R,
                                                      int r_is_f32) {
  __shared__ u16 As[64][136];  // pad +8 bf16 -> 2-way max bank aliasing (free)
  int tid = threadIdx.x;
  int wv = tid >> 6, lane = tid & 63;
  int m = lane & 15, quad = lane >> 4;
  int r0 = blockIdx.x * 64;

#pragma unroll
  for (int it = 0; it < 4; ++it) {
    int idx = it * 256 + tid;
    int row = idx >> 4, q = idx & 15;
    int grow = r0 + row;
    float4 v = make_float4(0.f, 0.f, 0.f, 0.f);
    if (grow < N_NODES) v = *(const float4*)(A + (size_t)grow * HID + q * 8);
    *(float4*)&As[row][q * 8] = v;
  }
  __syncthreads();

  const u16* WT = (wv < 2) ? WrelT : WrootT;
  int n0 = (wv & 1) * 64;

  f32x4 acc[4][4];
#pragma unroll
  for (int mt = 0; mt < 4; ++mt)
#pragma unroll
    for (int nt = 0; nt < 4; ++nt) acc[mt][nt] = (f32x4){0.f, 0.f, 0.f, 0.f};

#pragma unroll
  for (int ks = 0; ks < 4; ++ks) {
    int kb = ks * 32;
    bf16x8 af[4], bf[4];
#pragma unroll
    for (int mt = 0; mt < 4; ++mt)
      af[mt] = *(const bf16x8*)&As[mt * 16 + m][kb + quad * 8];
#pragma unroll
    for (int nt = 0; nt < 4; ++nt)
      bf[nt] = *(const bf16x8*)(WT + (size_t)(n0 + nt * 16 + m) * HID + kb + quad * 8);
#pragma unroll
    for (int mt = 0; mt < 4; ++mt)
#pragma unroll
      for (int nt = 0; nt < 4; ++nt)
        acc[mt][nt] = __builtin_amdgcn_mfma_f32_16x16x32_bf16(af[mt], bf[nt], acc[mt][nt], 0, 0, 0);
  }

  // Epilogue. C/D layout: col = lane&15, row = quad*4 + reg.
  if (wv < 2) {
#pragma unroll
    for (int mt = 0; mt < 4; ++mt) {
#pragma unroll
      for (int nt = 0; nt < 4; ++nt) {
        int col = n0 + nt * 16 + m;
#pragma unroll
        for (int r = 0; r < 4; ++r) {
          int row = r0 + mt * 16 + quad * 4 + r;
          if (row < N_NODES) Z[(size_t)row * HID + col] = f2bf(acc[mt][nt][r]);
        }
      }
    }
  } else {
    float bl[4];
#pragma unroll
    for (int nt = 0; nt < 4; ++nt) bl[nt] = bias[n0 + nt * 16 + m];
#pragma unroll
    for (int mt = 0; mt < 4; ++mt) {
#pragma unroll
      for (int nt = 0; nt < 4; ++nt) {
        int col = n0 + nt * 16 + m;
#pragma unroll
        for (int r = 0; r < 4; ++r) {
          int row = r0 + mt * 16 + quad * 4 + r;
          if (row < N_NODES) {
            float v = acc[mt][nt][r] + bl[nt];
            if (r_is_f32) ((float*)R)[(size_t)row * HID + col] = v;
            else          ((u16*)R)[(size_t)row * HID + col] = f2bf(v);
          }
        }
      }
    }
  }
}

// ---- gather helper: unrolled x2, 8 edges in flight per wave ----
// (round-11 lesson: predicated x4 regressed — VGPR 36->48, occupancy 44->32%,
// duplicate loads wasted BW. x2 is the sweet spot at mean degree 12.8.)
__device__ __forceinline__ void gather_node(const u16* __restrict__ Z,
                                            const int* __restrict__ esrc,
                                            int beg, int end, int q, int f8,
                                            f32x8& out) {
  f32x8 a0, a1;
#pragma unroll
  for (int j = 0; j < 8; ++j) { a0[j] = 0.f; a1[j] = 0.f; }
  int e = beg + q;
  for (; e + 4 < end; e += 8) {
    int s0 = esrc[e];
    int s1 = esrc[e + 4];
    u16x8 za = *(const u16x8*)(Z + (size_t)s0 * HID + f8);
    u16x8 zb = *(const u16x8*)(Z + (size_t)s1 * HID + f8);
#pragma unroll
    for (int j = 0; j < 8; ++j) { a0[j] += bf2f(za[j]); a1[j] += bf2f(zb[j]); }
  }
  if (e < end) {
    int s0 = esrc[e];
    u16x8 za = *(const u16x8*)(Z + (size_t)s0 * HID + f8);
#pragma unroll
    for (int j = 0; j < 8; ++j) a0[j] += bf2f(za[j]);
  }
#pragma unroll
  for (int j = 0; j < 8; ++j) out[j] = a0[j] + a1[j];
}

// ---------------- Edge aggregation (layer 1): OUT bf16 rmw + ReLU ----------------
__global__ __launch_bounds__(256) void agg_k(const u16* __restrict__ Z,
                                             const int* __restrict__ row_ptr,
                                             const int* __restrict__ esrc,
                                             u16* __restrict__ OUT) {
  int wave = threadIdx.x >> 6;
  int lane = threadIdx.x & 63;
  int node = blockIdx.x * 4 + wave;
  if (node >= N_NODES) return;
  int q = lane >> 4;        // 0..3
  int f8 = (lane & 15) * 8; // 8 features/lane
  int beg = row_ptr[node], end = row_ptr[node + 1];
  f32x8 acc;
  gather_node(Z, esrc, beg, end, q, f8, acc);
#pragma unroll
  for (int j = 0; j < 8; ++j) {
    acc[j] += __shfl_xor(acc[j], 16, 64);
    acc[j] += __shfl_xor(acc[j], 32, 64);
  }
  if (q == 0) {
    u16* o = OUT + (size_t)node * HID + f8;
    u16x8 o8 = *(const u16x8*)o;
    u16x8 w8;
#pragma unroll
    for (int j = 0; j < 8; ++j) w8[j] = f2bf(fmaxf(bf2f(o8[j]) + acc[j], 0.f));
    *(u16x8*)o = w8;
  }
}

// ---------------- Fused layer-2 agg + mean pool ----------------
// Quarter-private accumulators; shfl reduction only at segment-boundary flush.
__global__ __launch_bounds__(256) void pool_fused_k(const u16* __restrict__ Z,
                                                    const float* __restrict__ ROOT,
                                                    const int* __restrict__ row_ptr,
                                                    const int* __restrict__ esrc,
                                                    const int* __restrict__ batch,
                                                    float* __restrict__ pool,
                                                    int* __restrict__ cnt) {
  int wave = blockIdx.x * 4 + (threadIdx.x >> 6);
  int lane = threadIdx.x & 63;
  if (wave >= PNW) return;
  int q = lane >> 4;
  int f8 = (lane & 15) * 8;
  int n0 = wave * PCHUNK;
  int n1 = n0 + PCHUNK;
  if (n1 > N_NODES) n1 = N_NODES;
  int cur = batch[n0];
  int run = 0;
  float pacc[8];
#pragma unroll
  for (int j = 0; j < 8; ++j) pacc[j] = 0.f;

  auto flush = [&](int g) {
#pragma unroll
    for (int j = 0; j < 8; ++j) {
      pacc[j] += __shfl_xor(pacc[j], 16, 64);
      pacc[j] += __shfl_xor(pacc[j], 32, 64);
    }
    if (q == 0) {
#pragma unroll
      for (int j = 0; j < 8; ++j) atomicAdd(&pool[(size_t)g * HID + f8 + j], pacc[j]);
    }
    if (lane == 0) atomicAdd(&cnt[g], run);
#pragma unroll
    for (int j = 0; j < 8; ++j) pacc[j] = 0.f;
    run = 0;
  };

  for (int n = n0; n < n1; ++n) {
    int g = batch[n];  // wave-uniform
    if (g != cur) { flush(cur); cur = g; }
    int beg = row_ptr[n], end = row_ptr[n + 1];
    f32x8 acc;
    gather_node(Z, esrc, beg, end, q, f8, acc);
#pragma unroll
    for (int j = 0; j < 8; ++j) pacc[j] += acc[j];
    if ((n & 3) == q) {
      const float* rp = ROOT + (size_t)n * HID + f8;
      float4 ra = *(const float4*)rp;
      float4 rb = *(const float4*)(rp + 4);
      pacc[0] += ra.x; pacc[1] += ra.y; pacc[2] += ra.z; pacc[3] += ra.w;
      pacc[4] += rb.x; pacc[5] += rb.y; pacc[6] += rb.z; pacc[7] += rb.w;
    }
    run += 1;
  }
  flush(cur);
}

// ---------------- Final: sigmoid(pool/cnt @ Wlin + b) ----------------
__global__ __launch_bounds__(256) void final_k(const float* __restrict__ pool,
                                               const int* __restrict__ cnt,
                                               const float* __restrict__ Wlin,
                                               const float* __restrict__ blin,
                                               float* __restrict__ out) {
  int wave = threadIdx.x >> 6;
  int lane = threadIdx.x & 63;
  int g = blockIdx.x * 4 + wave;
  if (g >= NGRAPH) return;
  float2 p = *(const float2*)&pool[(size_t)g * HID + lane * 2];
  float v = p.x * Wlin[lane * 2 + 0] + p.y * Wlin[lane * 2 + 1];
#pragma unroll
  for (int off = 32; off; off >>= 1) v += __shfl_down(v, off, 64);
  if (lane == 0) {
    float c = (float)cnt[g];
    if (c < 1.f) c = 1.f;
    float logit = v / c + blin[0];
    out[g] = 1.f / (1.f + expf(-logit));
  }
}

extern "C" void kernel_launch(void* const* d_in, const int* in_sizes, int n_in,
                              void* d_out, int out_size, void* d_ws, size_t ws_size,
                              hipStream_t stream) {
  const float* x      = (const float*)d_in[0];
  const int*   ei     = (const int*)d_in[1];
  const int*   batch  = (const int*)d_in[2];
  const float* Wrel0  = (const float*)d_in[3];
  const float* brel0  = (const float*)d_in[4];
  const float* Wroot0 = (const float*)d_in[5];
  const float* Wrel1  = (const float*)d_in[6];
  const float* brel1  = (const float*)d_in[7];
  const float* Wroot1 = (const float*)d_in[8];
  const float* Wrel2  = (const float*)d_in[9];
  const float* brel2  = (const float*)d_in[10];
  const float* Wroot2 = (const float*)d_in[11];
  const float* Wlin   = (const float*)d_in[12];
  const float* blin   = (const float*)d_in[13];
  float* out = (float*)d_out;
  const int* srcp = ei;
  const int* dstp = ei + N_EDGES;

  char* ws = (char*)d_ws;
  size_t off = 0;
  auto alloc = [&](size_t b) { size_t o = off; off += (b + 255) & ~(size_t)255; return o; };
  u16*  Z     = (u16*)(ws + alloc(sizeof(u16) * N_NODES * HID));
  u16*  HA    = (u16*)(ws + alloc(sizeof(u16) * N_NODES * HID));
  u16*  HB    = (u16*)(ws + alloc(sizeof(u16) * N_NODES * HID));
  float* OUTF = (float*)(ws + alloc(sizeof(float) * N_NODES * HID));
  float* aggx = (float*)(ws + alloc(sizeof(float) * N_NODES * IN_DIM));
  u16* WT1rel = (u16*)(ws + alloc(sizeof(u16) * HID * HID));
  u16* WT1root= (u16*)(ws + alloc(sizeof(u16) * HID * HID));
  u16* WT2rel = (u16*)(ws + alloc(sizeof(u16) * HID * HID));
  u16* WT2root= (u16*)(ws + alloc(sizeof(u16) * HID * HID));
  int* row_ptr  = (int*)(ws + alloc(sizeof(int) * (N_NODES + 1)));
  int* esrc     = (int*)(ws + alloc(sizeof(int) * N_EDGES));
  int* fill_off = (int*)(ws + alloc(sizeof(int) * N_NODES));
  int* bsum     = (int*)(ws + alloc(sizeof(int) * 256));
  int* boff     = (int*)(ws + alloc(sizeof(int) * 256));
  size_t zero_base = off;
  int* counts  = (int*)(ws + alloc(sizeof(int) * N_NODES));
  float* pool  = (float*)(ws + alloc(sizeof(float) * NGRAPH * HID));
  int* cnt     = (int*)(ws + alloc(sizeof(int) * NGRAPH));
  size_t zero_len = off - zero_base;

  hipMemsetAsync(ws + zero_base, 0, zero_len, stream);

  setup_k<<<CNT_BLK + PREP_BLK, 256, 0, stream>>>(
      dstp, counts, Wrel1, Wroot1, Wrel2, Wroot2,
      WT1rel, WT1root, WT2rel, WT2root);
  partial_k<<<SCAN_NBLK, 256, 0, stream>>>(counts, bsum);
  scanb_k<<<1, 256, 0, stream>>>(bsum, boff, row_ptr);
  write_scan_k<<<SCAN_NBLK, 256, 0, stream>>>(counts, boff, row_ptr, fill_off);
  fill_edges_k<<<(N_EDGES + 255) / 256, 256, 0, stream>>>(srcp, dstp, fill_off, esrc);

  // Layer 0 in input space: gather x (20B/edge), then project once.
  gather_x_k<<<(N_NODES + 15) / 16, 256, 0, stream>>>(x, row_ptr, esrc, aggx);
  proj_l0_k<<<(N_NODES * HID + 255) / 256, 256, 0, stream>>>(aggx, x, Wrel0, Wroot0, brel0, HA);
  // Layer 1
  gemm_mfma_k<<<GEMM_NBLK, 256, 0, stream>>>(HA, WT1rel, WT1root, brel1, Z, HB, 0);
  agg_k<<<(N_NODES + 3) / 4, 256, 0, stream>>>(Z, row_ptr, esrc, HB);
  // Layer 2: gemm -> Z (rel, bf16) + OUTF (root+bias, f32); fused agg+pool
  gemm_mfma_k<<<GEMM_NBLK, 256, 0, stream>>>(HB, WT2rel, WT2root, brel2, Z, OUTF, 1);
  pool_fused_k<<<(PNW + 3) / 4, 256, 0, stream>>>(Z, OUTF, row_ptr, esrc, batch, pool, cnt);

  final_k<<<(NGRAPH + 3) / 4, 256, 0, stream>>>(pool, cnt, Wlin, blin, out);
}